// Round 5
// baseline (75.317 us; speedup 1.0000x reference)
//
#include <hip/hip_runtime.h>
#include <math.h>

#define NLEV   16
#define TSIZE  524288
#define TMASK  524287
#define NPIX   (1024*1024)

typedef __attribute__((ext_vector_type(8))) short s8v;
typedef __attribute__((ext_vector_type(4))) float f4v;

struct ResArr { float r[NLEV]; };
union Frag { unsigned int u[4]; s8v v; };

__device__ __forceinline__ unsigned short bf16_rn(float x) {
    unsigned int u = __builtin_bit_cast(unsigned int, x);
    u += 0x7fffu + ((u >> 16) & 1u);
    return (unsigned short)(u >> 16);
}
// truncating bf16 pack: one v_perm_b32 (values ~1e-4 vs 1e-2 threshold).
__device__ __forceinline__ unsigned int pk_bf16(float lo, float hi) {
    return __builtin_amdgcn_perm(__builtin_bit_cast(unsigned int, hi),
                                 __builtin_bit_cast(unsigned int, lo),
                                 0x07060302u);
}

// ws layout (float offsets): [0..15] res f32; [16..271] W3 padded [64][4] f32;
// at float offset 272: W1^T bf16 [64][32], then W2^T-permuted bf16 [64][64].
// W2's contraction dim is stored PERMUTED: physical k bits [st|g1 g0|j2 j1 j0]
// hold logical k bits [st|j2|g1 g0|j1 j0], so that layer-2 B-fragments are
// exactly the lane-local layer-1 output words (no LDS/shuffle exchange).
__global__ __launch_bounds__(256) void prep_kernel(
    const float* __restrict__ W1, const float* __restrict__ W2,
    const float* __restrict__ W3, float* __restrict__ ws, ResArr res)
{
    const int t = threadIdx.x;
    if (t < NLEV) ws[t] = res.r[t];
    float* w3p = ws + 16;
    unsigned short* w1t = (unsigned short*)(ws + 272);
    unsigned short* w2t = w1t + 64 * 32;
    for (int i = t; i < 64 * 4; i += 256) {
        int r = i >> 2, c = i & 3;
        w3p[i] = (c < 3) ? W3[r * 3 + c] : 0.0f;
    }
    for (int i = t; i < 64 * 32; i += 256) {
        int n = i >> 5, k = i & 31;
        w1t[i] = bf16_rn(W1[k * 64 + n]);
    }
    for (int i = t; i < 64 * 64; i += 256) {
        int n2 = i >> 6, kp = i & 63;
        int klog = (kp & 32) | ((kp & 4) << 2) | ((kp & 24) >> 1) | (kp & 3);
        w2t[i] = bf16_rn(W2[klog * 64 + n2]);
    }
}

// Block = 4 independent waves; wave wv covers rows yb+wv*4..+3, cols xb..xb+15.
// Lane (c15 = l&15, g = l>>4). GEMM pixel px = pt*16 + c15 = (x = xb+c15,
// y = yb+wv*4+pt). MLP in swapped form D' = W^T * act^T; h1 stays entirely in
// registers thanks to the W2 contraction-permutation (see prep). No LDS.
__global__ __launch_bounds__(256, 4) void ngp_mfma_kernel(
    const float* __restrict__ tables,
    const float* __restrict__ b1, const float* __restrict__ b2,
    const float* __restrict__ b3,
    const float* __restrict__ ws, float* __restrict__ out)
{
    const int tid  = threadIdx.x;
    const int lane = tid & 63;
    const int wv   = tid >> 6;
    const int c15  = lane & 15;
    const int g    = lane >> 4;
    const int xb   = blockIdx.x * 16;
    const int yb   = blockIdx.y * 16;

    const float4 rv = *(const float4*)(ws + g * 4);
    const float rr[4] = { rv.x, rv.y, rv.z, rv.w };
    const float xs = (float)(xb + c15) * (1.0f / 1024.0f);
    float yf[4];
    #pragma unroll
    for (int pt = 0; pt < 4; ++pt)
        yf[pt] = (float)(yb + wv * 4 + pt) * (1.0f / 1024.0f);

    const float2* __restrict__ tabg = (const float2*)tables + (size_t)(g * 4) * TSIZE;

    // ---- encode: per level j, issue all 16 gathers, then consume ----
    Frag bfrag[4];
    #pragma unroll
    for (int j = 0; j < 4; ++j) {
        const float r  = rr[j];
        const float sx = xs * r;
        const float fx0 = floorf(sx);
        const float fx  = sx - fx0;
        const unsigned int cx  = (unsigned int)fx0;
        const unsigned int cx1 = cx + 1u;
        const float2* __restrict__ tab = tabg + (size_t)j * TSIZE;
        float2 f[4][4];
        float fyv[4];
        #pragma unroll
        for (int pt = 0; pt < 4; ++pt) {
            const float sy  = yf[pt] * r;
            const float fy0 = floorf(sy);
            fyv[pt] = sy - fy0;
            const unsigned int cy  = (unsigned int)fy0;
            const unsigned int hy0 = cy * 2654435761u;
            const unsigned int hy1 = hy0 + 2654435761u;
            f[pt][0] = tab[(cx  ^ hy0) & TMASK];
            f[pt][1] = tab[(cx1 ^ hy0) & TMASK];
            f[pt][2] = tab[(cx  ^ hy1) & TMASK];
            f[pt][3] = tab[(cx1 ^ hy1) & TMASK];
        }
        #pragma unroll
        for (int pt = 0; pt < 4; ++pt) {
            const float fy  = fyv[pt];
            const float w00 = (1.0f - fx) * (1.0f - fy);
            const float w10 = fx          * (1.0f - fy);
            const float w01 = (1.0f - fx) * fy;
            const float w11 = fx          * fy;
            const float e0 = w00 * f[pt][0].x + w10 * f[pt][1].x
                           + w01 * f[pt][2].x + w11 * f[pt][3].x;
            const float e1 = w00 * f[pt][0].y + w10 * f[pt][1].y
                           + w01 * f[pt][2].y + w11 * f[pt][3].y;
            bfrag[pt].u[j] = pk_bf16(e0, e1);
        }
    }

    // ---- layer 1: D1'[n][px] = W1^T(64x32) * enc^T(32x64); bias+relu+pack
    //      into lane-local hp words (h1[n = mt*16+g*4+{r}] of px = pt*16+c15) ----
    const unsigned short* __restrict__ w1t = (const unsigned short*)(ws + 272);
    const unsigned short* __restrict__ w2t = w1t + 64 * 32;

    unsigned int hp[4][4][2];
    #pragma unroll
    for (int mt = 0; mt < 4; ++mt) {
        Frag afr;
        afr.v = *(const s8v*)(w1t + (mt * 16 + c15) * 32 + g * 8);
        const float4 bb = *(const float4*)(b1 + mt * 16 + g * 4);
        #pragma unroll
        for (int pt = 0; pt < 4; ++pt) {
            f4v acc = (f4v){0.f, 0.f, 0.f, 0.f};
            acc = __builtin_amdgcn_mfma_f32_16x16x32_bf16(
                afr.v, bfrag[pt].v, acc, 0, 0, 0);
            const float v0 = fmaxf(acc[0] + bb.x, 0.0f);
            const float v1 = fmaxf(acc[1] + bb.y, 0.0f);
            const float v2 = fmaxf(acc[2] + bb.z, 0.0f);
            const float v3 = fmaxf(acc[3] + bb.w, 0.0f);
            hp[mt][pt][0] = pk_bf16(v0, v1);
            hp[mt][pt][1] = pk_bf16(v2, v3);
        }
    }

    // ---- layer 2: B-frags are the lane's own hp words (k-permuted W2) ----
    f4v acc2[4][4];
    #pragma unroll
    for (int mt = 0; mt < 4; ++mt)
        #pragma unroll
        for (int pt = 0; pt < 4; ++pt)
            acc2[mt][pt] = (f4v){0.f, 0.f, 0.f, 0.f};
    #pragma unroll
    for (int st = 0; st < 2; ++st) {
        Frag a2[4], bf2[4];
        #pragma unroll
        for (int mt = 0; mt < 4; ++mt)
            a2[mt].v = *(const s8v*)(w2t + (mt * 16 + c15) * 64 + st * 32 + g * 8);
        #pragma unroll
        for (int pt = 0; pt < 4; ++pt) {
            bf2[pt].u[0] = hp[2 * st + 0][pt][0];
            bf2[pt].u[1] = hp[2 * st + 0][pt][1];
            bf2[pt].u[2] = hp[2 * st + 1][pt][0];
            bf2[pt].u[3] = hp[2 * st + 1][pt][1];
        }
        #pragma unroll
        for (int mt = 0; mt < 4; ++mt)
            #pragma unroll
            for (int pt = 0; pt < 4; ++pt)
                acc2[mt][pt] = __builtin_amdgcn_mfma_f32_16x16x32_bf16(
                    a2[mt].v, bf2[pt].v, acc2[mt][pt], 0, 0, 0);
    }

    // ---- bias + relu, layer 3 (64 -> 3) on VALU, butterfly over g ----
    const float* __restrict__ w3p = ws + 16;
    float part[4][3] = {{0,0,0},{0,0,0},{0,0,0},{0,0,0}};
    #pragma unroll
    for (int mt = 0; mt < 4; ++mt) {
        const float4 bb2 = *(const float4*)(b2 + mt * 16 + g * 4);
        const float bbv[4] = { bb2.x, bb2.y, bb2.z, bb2.w };
        #pragma unroll
        for (int r = 0; r < 4; ++r) {
            const float4 w3 = *(const float4*)(w3p + (size_t)(mt * 16 + g * 4 + r) * 4);
            #pragma unroll
            for (int pt = 0; pt < 4; ++pt) {
                const float h = fmaxf(acc2[mt][pt][r] + bbv[r], 0.0f);
                part[pt][0] = fmaf(h, w3.x, part[pt][0]);
                part[pt][1] = fmaf(h, w3.y, part[pt][1]);
                part[pt][2] = fmaf(h, w3.z, part[pt][2]);
            }
        }
    }
    #pragma unroll
    for (int pt = 0; pt < 4; ++pt)
        #pragma unroll
        for (int c = 0; c < 3; ++c) {
            float v = part[pt][c];
            v += __shfl_xor(v, 16);
            v += __shfl_xor(v, 32);
            part[pt][c] = v;
        }
    float o0 = 0.f, o1 = 0.f, o2 = 0.f;
    #pragma unroll
    for (int pt = 0; pt < 4; ++pt) {
        if (g == pt) { o0 = part[pt][0]; o1 = part[pt][1]; o2 = part[pt][2]; }
    }
    o0 += b3[0]; o1 += b3[1]; o2 += b3[2];
    const int pix = ((yb + wv * 4 + g) << 10) + xb + c15;
    out[0 * NPIX + pix] = 1.0f / (1.0f + __expf(-o0));
    out[1 * NPIX + pix] = 1.0f / (1.0f + __expf(-o1));
    out[2 * NPIX + pix] = 1.0f / (1.0f + __expf(-o2));
}

extern "C" void kernel_launch(void* const* d_in, const int* in_sizes, int n_in,
                              void* d_out, int out_size, void* d_ws, size_t ws_size,
                              hipStream_t stream) {
    const float* tables = (const float*)d_in[0];
    const float* W1     = (const float*)d_in[1];
    const float* b1     = (const float*)d_in[2];
    const float* W2     = (const float*)d_in[3];
    const float* b2     = (const float*)d_in[4];
    const float* W3     = (const float*)d_in[5];
    const float* b3     = (const float*)d_in[6];
    float* out          = (float*)d_out;
    float* ws           = (float*)d_ws;

    ResArr res;
    const double growth = exp((log(1024.0) - log(16.0)) / 15.0);
    for (int l = 0; l < NLEV; ++l)
        res.r[l] = (float)floor(16.0 * pow(growth, (double)l));

    hipLaunchKernelGGL(prep_kernel, dim3(1), dim3(256), 0, stream, W1, W2, W3, ws, res);
    hipLaunchKernelGGL(ngp_mfma_kernel, dim3(64, 64), dim3(256), 0, stream,
                       tables, b1, b2, b3, ws, out);
}

// Round 6
// 73.259 us; speedup vs baseline: 1.0281x; 1.0281x over previous
//
#include <hip/hip_runtime.h>
#include <math.h>

#define NLEV   16
#define TSIZE  524288
#define TMASK  524287
#define NPIX   (1024*1024)

typedef __attribute__((ext_vector_type(8))) short s8v;
typedef __attribute__((ext_vector_type(4))) float f4v;

struct ResArr { float r[NLEV]; };
union Frag { unsigned int u[4]; s8v v; };

__device__ __forceinline__ unsigned short bf16_rn(float x) {
    unsigned int u = __builtin_bit_cast(unsigned int, x);
    u += 0x7fffu + ((u >> 16) & 1u);
    return (unsigned short)(u >> 16);
}
// truncating bf16 pack: one v_perm_b32 (values ~1e-4 vs 1e-2 threshold).
__device__ __forceinline__ unsigned int pk_bf16(float lo, float hi) {
    return __builtin_amdgcn_perm(__builtin_bit_cast(unsigned int, hi),
                                 __builtin_bit_cast(unsigned int, lo),
                                 0x07060302u);
}

// ws layout (float offsets): [0..15] res f32; [16..271] W3 padded [64][4] f32;
// at float offset 272: W1^T bf16 [64][32], then W2^T-permuted bf16 [64][64].
// W2's contraction dim is stored PERMUTED: physical k bits [st|g1 g0|j2 j1 j0]
// hold logical k bits [st|j2|g1 g0|j1 j0], so that layer-2 B-fragments are
// exactly the lane-local layer-1 output words (no LDS/shuffle exchange).
__global__ __launch_bounds__(256) void prep_kernel(
    const float* __restrict__ W1, const float* __restrict__ W2,
    const float* __restrict__ W3, float* __restrict__ ws, ResArr res)
{
    const int t = threadIdx.x;
    if (t < NLEV) ws[t] = res.r[t];
    float* w3p = ws + 16;
    unsigned short* w1t = (unsigned short*)(ws + 272);
    unsigned short* w2t = w1t + 64 * 32;
    for (int i = t; i < 64 * 4; i += 256) {
        int r = i >> 2, c = i & 3;
        w3p[i] = (c < 3) ? W3[r * 3 + c] : 0.0f;
    }
    for (int i = t; i < 64 * 32; i += 256) {
        int n = i >> 5, k = i & 31;
        w1t[i] = bf16_rn(W1[k * 64 + n]);
    }
    for (int i = t; i < 64 * 64; i += 256) {
        int n2 = i >> 6, kp = i & 63;
        int klog = (kp & 32) | ((kp & 4) << 2) | ((kp & 24) >> 1) | (kp & 3);
        w2t[i] = bf16_rn(W2[klog * 64 + n2]);
    }
}

// Block = 4 independent waves; wave wv covers rows yb+wv*4..+3, cols xb..xb+15.
// Lane (c15 = l&15, g = l>>4). GEMM pixel px = pt*16 + c15 = (x = xb+c15,
// y = yb+wv*4+pt). MLP in swapped form D' = W^T * act^T; h1 stays entirely in
// registers thanks to the W2 contraction-permutation (see prep). No LDS.
// launch_bounds(256,2): round-5's (256,4) made the allocator clamp to 64 VGPR
// and spill ~14 MB/dispatch to scratch (WRITE_SIZE 12->26 MB). Cap 256 here;
// peak live state (bfrag+hp+acc2+gather batch) needs ~130 VGPR.
__global__ __launch_bounds__(256, 2) void ngp_mfma_kernel(
    const float* __restrict__ tables,
    const float* __restrict__ b1, const float* __restrict__ b2,
    const float* __restrict__ b3,
    const float* __restrict__ ws, float* __restrict__ out)
{
    const int tid  = threadIdx.x;
    const int lane = tid & 63;
    const int wv   = tid >> 6;
    const int c15  = lane & 15;
    const int g    = lane >> 4;
    const int xb   = blockIdx.x * 16;
    const int yb   = blockIdx.y * 16;

    const float4 rv = *(const float4*)(ws + g * 4);
    const float rr[4] = { rv.x, rv.y, rv.z, rv.w };
    const float xs = (float)(xb + c15) * (1.0f / 1024.0f);
    float yf[4];
    #pragma unroll
    for (int pt = 0; pt < 4; ++pt)
        yf[pt] = (float)(yb + wv * 4 + pt) * (1.0f / 1024.0f);

    const float2* __restrict__ tabg = (const float2*)tables + (size_t)(g * 4) * TSIZE;

    // ---- encode: per level j, issue all 16 gathers, then consume ----
    Frag bfrag[4];
    #pragma unroll
    for (int j = 0; j < 4; ++j) {
        const float r  = rr[j];
        const float sx = xs * r;
        const float fx0 = floorf(sx);
        const float fx  = sx - fx0;
        const unsigned int cx  = (unsigned int)fx0;
        const unsigned int cx1 = cx + 1u;
        const float2* __restrict__ tab = tabg + (size_t)j * TSIZE;
        float2 f[4][4];
        float fyv[4];
        #pragma unroll
        for (int pt = 0; pt < 4; ++pt) {
            const float sy  = yf[pt] * r;
            const float fy0 = floorf(sy);
            fyv[pt] = sy - fy0;
            const unsigned int cy  = (unsigned int)fy0;
            const unsigned int hy0 = cy * 2654435761u;
            const unsigned int hy1 = hy0 + 2654435761u;
            f[pt][0] = tab[(cx  ^ hy0) & TMASK];
            f[pt][1] = tab[(cx1 ^ hy0) & TMASK];
            f[pt][2] = tab[(cx  ^ hy1) & TMASK];
            f[pt][3] = tab[(cx1 ^ hy1) & TMASK];
        }
        #pragma unroll
        for (int pt = 0; pt < 4; ++pt) {
            const float fy  = fyv[pt];
            const float w00 = (1.0f - fx) * (1.0f - fy);
            const float w10 = fx          * (1.0f - fy);
            const float w01 = (1.0f - fx) * fy;
            const float w11 = fx          * fy;
            const float e0 = w00 * f[pt][0].x + w10 * f[pt][1].x
                           + w01 * f[pt][2].x + w11 * f[pt][3].x;
            const float e1 = w00 * f[pt][0].y + w10 * f[pt][1].y
                           + w01 * f[pt][2].y + w11 * f[pt][3].y;
            bfrag[pt].u[j] = pk_bf16(e0, e1);
        }
    }

    // ---- layer 1: D1'[n][px] = W1^T(64x32) * enc^T(32x64); bias+relu+pack
    //      into lane-local hp words (h1[n = mt*16+g*4+{r}] of px = pt*16+c15) ----
    const unsigned short* __restrict__ w1t = (const unsigned short*)(ws + 272);
    const unsigned short* __restrict__ w2t = w1t + 64 * 32;

    unsigned int hp[4][4][2];
    #pragma unroll
    for (int mt = 0; mt < 4; ++mt) {
        Frag afr;
        afr.v = *(const s8v*)(w1t + (mt * 16 + c15) * 32 + g * 8);
        const float4 bb = *(const float4*)(b1 + mt * 16 + g * 4);
        #pragma unroll
        for (int pt = 0; pt < 4; ++pt) {
            f4v acc = (f4v){0.f, 0.f, 0.f, 0.f};
            acc = __builtin_amdgcn_mfma_f32_16x16x32_bf16(
                afr.v, bfrag[pt].v, acc, 0, 0, 0);
            const float v0 = fmaxf(acc[0] + bb.x, 0.0f);
            const float v1 = fmaxf(acc[1] + bb.y, 0.0f);
            const float v2 = fmaxf(acc[2] + bb.z, 0.0f);
            const float v3 = fmaxf(acc[3] + bb.w, 0.0f);
            hp[mt][pt][0] = pk_bf16(v0, v1);
            hp[mt][pt][1] = pk_bf16(v2, v3);
        }
    }

    // ---- layer 2: B-frags are the lane's own hp words (k-permuted W2) ----
    f4v acc2[4][4];
    #pragma unroll
    for (int mt = 0; mt < 4; ++mt)
        #pragma unroll
        for (int pt = 0; pt < 4; ++pt)
            acc2[mt][pt] = (f4v){0.f, 0.f, 0.f, 0.f};
    #pragma unroll
    for (int st = 0; st < 2; ++st) {
        Frag a2[4], bf2[4];
        #pragma unroll
        for (int mt = 0; mt < 4; ++mt)
            a2[mt].v = *(const s8v*)(w2t + (mt * 16 + c15) * 64 + st * 32 + g * 8);
        #pragma unroll
        for (int pt = 0; pt < 4; ++pt) {
            bf2[pt].u[0] = hp[2 * st + 0][pt][0];
            bf2[pt].u[1] = hp[2 * st + 0][pt][1];
            bf2[pt].u[2] = hp[2 * st + 1][pt][0];
            bf2[pt].u[3] = hp[2 * st + 1][pt][1];
        }
        #pragma unroll
        for (int mt = 0; mt < 4; ++mt)
            #pragma unroll
            for (int pt = 0; pt < 4; ++pt)
                acc2[mt][pt] = __builtin_amdgcn_mfma_f32_16x16x32_bf16(
                    a2[mt].v, bf2[pt].v, acc2[mt][pt], 0, 0, 0);
    }

    // ---- bias + relu, layer 3 (64 -> 3) on VALU, butterfly over g ----
    const float* __restrict__ w3p = ws + 16;
    float part[4][3] = {{0,0,0},{0,0,0},{0,0,0},{0,0,0}};
    #pragma unroll
    for (int mt = 0; mt < 4; ++mt) {
        const float4 bb2 = *(const float4*)(b2 + mt * 16 + g * 4);
        const float bbv[4] = { bb2.x, bb2.y, bb2.z, bb2.w };
        #pragma unroll
        for (int r = 0; r < 4; ++r) {
            const float4 w3 = *(const float4*)(w3p + (size_t)(mt * 16 + g * 4 + r) * 4);
            #pragma unroll
            for (int pt = 0; pt < 4; ++pt) {
                const float h = fmaxf(acc2[mt][pt][r] + bbv[r], 0.0f);
                part[pt][0] = fmaf(h, w3.x, part[pt][0]);
                part[pt][1] = fmaf(h, w3.y, part[pt][1]);
                part[pt][2] = fmaf(h, w3.z, part[pt][2]);
            }
        }
    }
    #pragma unroll
    for (int pt = 0; pt < 4; ++pt)
        #pragma unroll
        for (int c = 0; c < 3; ++c) {
            float v = part[pt][c];
            v += __shfl_xor(v, 16);
            v += __shfl_xor(v, 32);
            part[pt][c] = v;
        }
    float o0 = 0.f, o1 = 0.f, o2 = 0.f;
    #pragma unroll
    for (int pt = 0; pt < 4; ++pt) {
        if (g == pt) { o0 = part[pt][0]; o1 = part[pt][1]; o2 = part[pt][2]; }
    }
    o0 += b3[0]; o1 += b3[1]; o2 += b3[2];
    const int pix = ((yb + wv * 4 + g) << 10) + xb + c15;
    out[0 * NPIX + pix] = 1.0f / (1.0f + __expf(-o0));
    out[1 * NPIX + pix] = 1.0f / (1.0f + __expf(-o1));
    out[2 * NPIX + pix] = 1.0f / (1.0f + __expf(-o2));
}

extern "C" void kernel_launch(void* const* d_in, const int* in_sizes, int n_in,
                              void* d_out, int out_size, void* d_ws, size_t ws_size,
                              hipStream_t stream) {
    const float* tables = (const float*)d_in[0];
    const float* W1     = (const float*)d_in[1];
    const float* b1     = (const float*)d_in[2];
    const float* W2     = (const float*)d_in[3];
    const float* b2     = (const float*)d_in[4];
    const float* W3     = (const float*)d_in[5];
    const float* b3     = (const float*)d_in[6];
    float* out          = (float*)d_out;
    float* ws           = (float*)d_ws;

    ResArr res;
    const double growth = exp((log(1024.0) - log(16.0)) / 15.0);
    for (int l = 0; l < NLEV; ++l)
        res.r[l] = (float)floor(16.0 * pow(growth, (double)l));

    hipLaunchKernelGGL(prep_kernel, dim3(1), dim3(256), 0, stream, W1, W2, W3, ws, res);
    hipLaunchKernelGGL(ngp_mfma_kernel, dim3(64, 64), dim3(256), 0, stream,
                       tables, b1, b2, b3, ws, out);
}